// Round 9
// baseline (539.703 us; speedup 1.0000x reference)
//
#include <hip/hip_runtime.h>

// MultiheadFlashLinearEnsemble: B=2,T=2048,E=2048,H=16,HKV=4,M=4,HD=32,NREP=4
// cvt_all->f16 -> GEMM+rope fused -> lstats (softmax denoms, diag-only mask)
// -> attn v8: BARRIER-FREE k-loop. Block = 16 q-rows x 2 waves; wave w owns
// k-cols [32w,32w+32) of each 64-tile (all 4 ensembles, combined in regs);
// P slice wave-private (own k-cols -> own partial PV, k-split summed in
// epilogue). K/V read direct from global (L2). 4096 waves = 16/CU.
// -> RMSnorm -> GEMM(out).

typedef unsigned short u16;
typedef unsigned int u32;
typedef _Float16 f16;
typedef _Float16 f16x8 __attribute__((ext_vector_type(8)));
typedef float f32x4 __attribute__((ext_vector_type(4)));

#define B_ 2
#define T_ 2048
#define E_ 2048
#define H_ 16
#define HKV_ 4
#define M_ 4
#define HD_ 32
// (1/sqrt(32)) * log2(e): q-scores in log2 domain -> exp2f = raw v_exp_f32
#define SCALE_Q 0.2550348873f

#define GLOAD_LDS(g, l)                                                   \
  __builtin_amdgcn_global_load_lds(                                       \
      (const __attribute__((address_space(1))) u32*)(g),                  \
      (__attribute__((address_space(3))) u32*)(l), 16, 0, 0)

__device__ __forceinline__ u16 f2h(float f) {
  f16 h = (f16)f;
  return __builtin_bit_cast(u16, h);
}

// One launch converts all five f32 tensors to f16 (blockIdx.y = region).
__global__ void cvt_all(const float* __restrict__ x, const float* __restrict__ qw,
                        const float* __restrict__ kw, const float* __restrict__ vw,
                        const float* __restrict__ ow, u16* __restrict__ xb,
                        u16* __restrict__ wcat, u16* __restrict__ wo16) {
  const float* src;
  u16* dst;
  int n4;
  switch (blockIdx.y) {
    case 0: src = x;  dst = xb;            n4 = 2097152; break;
    case 1: src = qw; dst = wcat;          n4 = 1048576; break;
    case 2: src = kw; dst = wcat + 4194304; n4 = 262144; break;
    case 3: src = vw; dst = wcat + 5242880; n4 = 262144; break;
    default: src = ow; dst = wo16;         n4 = 1048576; break;
  }
  int i = blockIdx.x * blockDim.x + threadIdx.x;
  if (i < n4) {
    float4 v = ((const float4*)src)[i];
    ushort4 o;
    o.x = f2h(v.x); o.y = f2h(v.y); o.z = f2h(v.z); o.w = f2h(v.w);
    ((ushort4*)dst)[i] = o;
  }
}

// ---- GEMM core macro: 128x128 tile, BK=32, acc[4][4] per wave ----
#define GEMM_CORE(A_, B_ptr, K_)                                              \
  for (int k0 = 0; k0 < (K_); k0 += 32) {                                     \
    _Pragma("unroll") for (int j = 0; j < 2; ++j) {                           \
      GLOAD_LDS(&(A_)[(size_t)(m0 + r0 + j * 64) * (K_) + k0 + c8],           \
                &As[tid * 8 + j * 2048]);                                     \
      GLOAD_LDS(&(B_ptr)[(size_t)(n0 + r0 + j * 64) * (K_) + k0 + c8],        \
                &Bs[tid * 8 + j * 2048]);                                     \
    }                                                                         \
    __syncthreads();                                                          \
    f16x8 af[4], bfr[4];                                                      \
    _Pragma("unroll") for (int mt = 0; mt < 4; ++mt)                          \
        af[mt] = *(const f16x8*)&As[(wm + mt * 16 + r) * 32 + g * 8];         \
    _Pragma("unroll") for (int nt = 0; nt < 4; ++nt)                          \
        bfr[nt] = *(const f16x8*)&Bs[(wn + nt * 16 + r) * 32 + g * 8];        \
    _Pragma("unroll") for (int mt = 0; mt < 4; ++mt)                          \
        _Pragma("unroll") for (int nt = 0; nt < 4; ++nt)                      \
            acc[mt][nt] = __builtin_amdgcn_mfma_f32_16x16x32_f16(             \
                af[mt], bfr[nt], acc[mt][nt], 0, 0, 0);                       \
    __syncthreads();                                                          \
  }

// out = normed @ out_w^T, plain f32 C write.
__global__ __launch_bounds__(256) void gemm_bt(const u16* __restrict__ A,
                                               const u16* __restrict__ Bm,
                                               float* __restrict__ C,
                                               int M, int N, int K) {
  __shared__ __align__(16) u16 As[128 * 32];
  __shared__ __align__(16) u16 Bs[128 * 32];
  const int tid = threadIdx.x;
  const int lane = tid & 63;
  const int wv = tid >> 6;
  const int g = lane >> 4;
  const int r = lane & 15;
  const int m0 = blockIdx.y * 128;
  const int n0 = blockIdx.x * 128;
  const int wm = (wv >> 1) * 64;
  const int wn = (wv & 1) * 64;
  f32x4 acc[4][4];
#pragma unroll
  for (int a = 0; a < 4; ++a)
#pragma unroll
    for (int b = 0; b < 4; ++b) acc[a][b] = (f32x4){0.f, 0.f, 0.f, 0.f};
  const int r0 = tid >> 2;
  const int c8 = (tid & 3) << 3;

  GEMM_CORE(A, Bm, K)

#pragma unroll
  for (int mt = 0; mt < 4; ++mt)
#pragma unroll
    for (int nt = 0; nt < 4; ++nt) {
      int row = m0 + wm + mt * 16 + g * 4;
      int col = n0 + wn + nt * 16 + r;
#pragma unroll
      for (int rr = 0; rr < 4; ++rr)
        C[(size_t)(row + rr) * N + col] = acc[mt][nt][rr];
    }
}

// qkv GEMM with FUSED rotary + repack epilogue. N=3072; each 128-col block
// lies wholly in one region: bx 0-15 q, 16-19 k, 20-23 v.
__global__ __launch_bounds__(256) void gemm_qkv_rope(
    const u16* __restrict__ A, const u16* __restrict__ Bm,
    const float* __restrict__ cosb, const float* __restrict__ sinb,
    u16* __restrict__ qp, u16* __restrict__ kp, u16* __restrict__ vtp) {
  __shared__ __align__(16) u16 As[128 * 32];
  __shared__ __align__(16) u16 Bs[128 * 32];
  const int tid = threadIdx.x;
  const int lane = tid & 63;
  const int wv = tid >> 6;
  const int g = lane >> 4;
  const int r = lane & 15;
  const int m0 = blockIdx.y * 128;
  const int n0 = blockIdx.x * 128;
  const int wm = (wv >> 1) * 64;
  const int wn = (wv & 1) * 64;
  f32x4 acc[4][4];
#pragma unroll
  for (int a = 0; a < 4; ++a)
#pragma unroll
    for (int b = 0; b < 4; ++b) acc[a][b] = (f32x4){0.f, 0.f, 0.f, 0.f};
  const int r0 = tid >> 2;
  const int c8 = (tid & 3) << 3;

  GEMM_CORE(A, Bm, 2048)

  const int b = m0 >> 11;                 // block-uniform batch
  const float signf = (r & 1) ? 1.f : -1.f;
  const int jb = r >> 1;                  // j for even nt; odd nt -> jb+8

  if (n0 < 2048) {
#pragma unroll
    for (int mt = 0; mt < 4; ++mt) {
      int row = m0 + wm + mt * 16 + g * 4;
      int t0 = row & 2047;
#pragma unroll
      for (int rr = 0; rr < 4; ++rr) {
        int t = t0 + rr;
        float c0 = cosb[t * 16 + jb], s0 = sinb[t * 16 + jb];
        float c1 = cosb[t * 16 + 8 + jb], s1 = sinb[t * 16 + 8 + jb];
#pragma unroll
        for (int nt = 0; nt < 4; ++nt) {
          float xv = acc[mt][nt][rr];
          float pv = __shfl_xor(xv, 1, 64);
          float c = (nt & 1) ? c1 : c0;
          float s = (nt & 1) ? s1 : s0;
          float o = (xv * c + signf * pv * s) * SCALE_Q;
          int col = n0 + wn + nt * 16 + r;
          int hh = col >> 7, mm = (col >> 5) & 3, d = col & 31;
          qp[((((size_t)b * H_ + hh) * M_ + mm) * T_ + t) * HD_ + d] = f2h(o);
        }
      }
    }
  } else if (n0 < 2560) {
#pragma unroll
    for (int mt = 0; mt < 4; ++mt) {
      int row = m0 + wm + mt * 16 + g * 4;
      int t0 = row & 2047;
#pragma unroll
      for (int rr = 0; rr < 4; ++rr) {
        int t = t0 + rr;
        float c0 = cosb[t * 16 + jb], s0 = sinb[t * 16 + jb];
        float c1 = cosb[t * 16 + 8 + jb], s1 = sinb[t * 16 + 8 + jb];
#pragma unroll
        for (int nt = 0; nt < 4; ++nt) {
          float xv = acc[mt][nt][rr];
          float pv = __shfl_xor(xv, 1, 64);
          float c = (nt & 1) ? c1 : c0;
          float s = (nt & 1) ? s1 : s0;
          float o = xv * c + signf * pv * s;
          int col2 = n0 + wn + nt * 16 + r - 2048;
          int hh = col2 >> 7, mm = (col2 >> 5) & 3, d = col2 & 31;
          kp[((((size_t)b * HKV_ + hh) * M_ + mm) * T_ + t) * HD_ + d] = f2h(o);
        }
      }
    }
  } else {
#pragma unroll
    for (int mt = 0; mt < 4; ++mt) {
      int row = m0 + wm + mt * 16 + g * 4;
      int t0 = row & 2047;
#pragma unroll
      for (int nt = 0; nt < 4; ++nt) {
        int col3 = n0 + wn + nt * 16 + r - 2560;
        int hkv = col3 >> 7, e = col3 & 127;
        ushort4 w;
        w.x = f2h(acc[mt][nt][0]);
        w.y = f2h(acc[mt][nt][1]);
        w.z = f2h(acc[mt][nt][2]);
        w.w = f2h(acc[mt][nt][3]);
        *(ushort4*)&vtp[(((size_t)b * HKV_ + hkv) * 128 + e) * T_ + t0] = w;
      }
    }
  }
}

// Softmax denom prepass: invw[b][h][e][row] = tanh(rawW[e])*ws / sum exp2(s').
// Wave = 16-row strip; PAIRED strips (s, 127-s). Mask only on diagonal tile.
__global__ __launch_bounds__(256) void lstats_kernel(
    const u16* __restrict__ qp, const u16* __restrict__ kp,
    const float* __restrict__ rawW, const float* __restrict__ wscale,
    float* __restrict__ invw) {
  const int tid = threadIdx.x;
  const int lane = tid & 63;
  const int wv = tid >> 6;
  const int g = lane >> 4, r = lane & 15;
  const int h = blockIdx.y;
  const int b = blockIdx.z >> 2, e = blockIdx.z & 3;
  const int hkv = h >> 2;
  const int s0 = blockIdx.x * 4 + wv;  // strip 0..63; pair = 127-s0

  const size_t qb = (((size_t)b * H_ + h) * M_ + e) * T_ * HD_;
  const size_t kb = (((size_t)b * HKV_ + hkv) * M_ + e) * T_ * HD_;
  const float mw = tanhf(rawW[e]) * wscale[0];

  for (int ps = 0; ps < 2; ++ps) {
    const int strip = ps ? 127 - s0 : s0;
    const int q0 = strip * 16;
    f16x8 qf = *(const f16x8*)&qp[qb + (size_t)(q0 + r) * HD_ + g * 8];
    float lacc[4] = {0.f, 0.f, 0.f, 0.f};

    for (int k0 = 0; k0 < q0 + 16; k0 += 64) {
      f32x4 s[4];
#pragma unroll
      for (int nt = 0; nt < 4; ++nt) {
        f16x8 kf = *(const f16x8*)&kp[kb + (size_t)(k0 + nt * 16 + r) * HD_ + g * 8];
        s[nt] = __builtin_amdgcn_mfma_f32_16x16x32_f16(qf, kf, (f32x4){0.f, 0.f, 0.f, 0.f}, 0, 0, 0);
      }
      if (k0 + 63 > q0) {  // diagonal tile: mask needed
#pragma unroll
        for (int rr = 0; rr < 4; ++rr) {
          int row = q0 + g * 4 + rr;
#pragma unroll
          for (int nt = 0; nt < 4; ++nt) {
            int col = k0 + nt * 16 + r;
            float sv = (col <= row) ? s[nt][rr] : -1e30f;
            lacc[rr] += exp2f(sv);
          }
        }
      } else {
#pragma unroll
        for (int rr = 0; rr < 4; ++rr)
#pragma unroll
          for (int nt = 0; nt < 4; ++nt) lacc[rr] += exp2f(s[nt][rr]);
      }
    }
#pragma unroll
    for (int rr = 0; rr < 4; ++rr) {
      float l = lacc[rr];
#pragma unroll
      for (int off = 8; off >= 1; off >>= 1) l += __shfl_xor(l, off, 64);
      if (r == 0)
        invw[(((size_t)b * H_ + h) * M_ + e) * T_ + q0 + g * 4 + rr] = mw / l;
    }
  }
}

// attn v8: block = 16 q-rows (paired strips bx, 127-bx), 128 threads.
// Wave w owns k-cols [32w,32w+32) of each 64-wide tile: QK (4e x 2nt MFMA),
// exp2+combine in regs, wave-PRIVATE Pc slice, partial PV over own k-cols
// (all 128 e-cols). NO barriers in the k-loop. K/V direct from global.
// Epilogue: sum the two k-half partials in LDS, RMSnorm, store.
__global__ __launch_bounds__(128, 4) void attn_kernel(
    const u16* __restrict__ qp, const u16* __restrict__ kp,
    const u16* __restrict__ vtp, const float* __restrict__ invw,
    const float* __restrict__ gamma, u16* __restrict__ normed) {
  __shared__ __align__(16) char smem[19200];
  u16* Pc = (u16*)smem;                  // [2 waves][16][36] f16 = 2304 B
  float* comb = (float*)(smem + 2304);   // [2 waves][16][132] f32 = 16896 B

  const int tid = threadIdx.x;
  const int lane = tid & 63;
  const int wv = tid >> 6;  // k-half owner
  const int g = lane >> 4;
  const int r = lane & 15;
  const int h = blockIdx.y;
  const int b = blockIdx.z;
  const int hkv = h >> 2;

  const size_t qb = ((size_t)b * H_ + h) * M_ * T_ * HD_;
  const size_t kb = ((size_t)b * HKV_ + hkv) * M_ * T_ * HD_;
  const size_t vb = ((size_t)b * HKV_ + hkv) * 128 * (size_t)T_;

  for (int ps = 0; ps < 2; ++ps) {
    const int q0 = (ps ? 127 - blockIdx.x : blockIdx.x) * 16;

    f16x8 qf[4];
    float iw[4][4];
#pragma unroll
    for (int e = 0; e < 4; ++e) {
      qf[e] = *(const f16x8*)&qp[qb + ((size_t)e * T_ + q0 + r) * HD_ + g * 8];
      const float* ivp = invw + (((size_t)b * H_ + h) * M_ + e) * T_;
#pragma unroll
      for (int rr = 0; rr < 4; ++rr) iw[e][rr] = ivp[q0 + g * 4 + rr];
    }

    // acc[ct]: row = g*4+rr (local q-row), col = ct*16+r (e-col); own k-half
    f32x4 acc[8];
#pragma unroll
    for (int ct = 0; ct < 8; ++ct) acc[ct] = (f32x4){0.f, 0.f, 0.f, 0.f};

    const int niter = q0 / 64 + 1;
    for (int i = 0; i < niter; ++i) {
      const int k0 = i * 64 + wv * 32;  // this wave's k-base
      if (k0 > q0 + 15) continue;       // half-tile fully masked

      // V fragments: all 128 e-cols x own 32 k (direct global, L2-hot)
      f16x8 vf[8];
#pragma unroll
      for (int ct = 0; ct < 8; ++ct)
        vf[ct] = *(const f16x8*)&vtp[vb + (size_t)(ct * 16 + r) * T_ + k0 + g * 8];

      // ---- QK + exp2 + in-register ensemble combine (own k-cols) ----
      float pc[2][4];
#pragma unroll
      for (int nt = 0; nt < 2; ++nt)
#pragma unroll
        for (int rr = 0; rr < 4; ++rr) pc[nt][rr] = 0.f;
      const bool need_mask = (k0 + 31 > q0);
#pragma unroll
      for (int e = 0; e < 4; ++e) {
        f32x4 s[2];
#pragma unroll
        for (int nt = 0; nt < 2; ++nt) {
          f16x8 kf = *(const f16x8*)&kp[kb + ((size_t)e * T_ + k0 + nt * 16 + r) * HD_ + g * 8];
          s[nt] = __builtin_amdgcn_mfma_f32_16x16x32_f16(qf[e], kf, (f32x4){0.f, 0.f, 0.f, 0.f}, 0, 0, 0);
        }
#pragma unroll
        for (int nt = 0; nt < 2; ++nt)
#pragma unroll
          for (int rr = 0; rr < 4; ++rr) {
            float sv = s[nt][rr];
            if (need_mask && (k0 + nt * 16 + r > q0 + g * 4 + rr)) sv = -1e30f;
            pc[nt][rr] = fmaf(exp2f(sv), iw[e][rr], pc[nt][rr]);
          }
      }

      // ---- wave-private P round-trip (in-wave lgkm ordering only) ----
      u16* myP = Pc + wv * 576;
#pragma unroll
      for (int nt = 0; nt < 2; ++nt)
#pragma unroll
        for (int rr = 0; rr < 4; ++rr)
          myP[(g * 4 + rr) * 36 + nt * 16 + r] = f2h(pc[nt][rr]);
      f16x8 pf = *(const f16x8*)&myP[r * 36 + g * 8];

      // ---- partial PV: own k-half, all 128 e-cols ----
#pragma unroll
      for (int ct = 0; ct < 8; ++ct)
        acc[ct] = __builtin_amdgcn_mfma_f32_16x16x32_f16(pf, vf[ct], acc[ct], 0, 0, 0);
    }

    // ---- epilogue: sum k-half partials, RMSnorm, store ----
#pragma unroll
    for (int ct = 0; ct < 8; ++ct)
#pragma unroll
      for (int rr = 0; rr < 4; ++rr)
        comb[(wv * 16 + g * 4 + rr) * 132 + ct * 16 + r] = acc[ct][rr];
    __syncthreads();

    {
      int row = tid >> 3;        // 0..15
      int ch = (tid & 7) * 16;   // 16-col chunk
      float vals[16];
      float ss = 0.f;
#pragma unroll
      for (int e2 = 0; e2 < 16; ++e2) {
        float v = comb[row * 132 + ch + e2] + comb[(16 + row) * 132 + ch + e2];
        vals[e2] = v;
        ss += v * v;
      }
      ss += __shfl_xor(ss, 1, 64);
      ss += __shfl_xor(ss, 2, 64);
      ss += __shfl_xor(ss, 4, 64);
      float rstd = rsqrtf(ss * (1.f / 128.f) + 1e-5f);
      size_t obase = ((size_t)b * T_ + q0 + row) * E_ + (size_t)h * 128 + ch;
      union { u16 u[16]; uint4 q[2]; } pk;
#pragma unroll
      for (int e2 = 0; e2 < 16; ++e2)
        pk.u[e2] = f2h(vals[e2] * rstd * gamma[ch + e2]);
      *(uint4*)&normed[obase] = pk.q[0];
      *(uint4*)&normed[obase + 8] = pk.q[1];
    }
    __syncthreads();  // RMS reads done before next pass overwrites comb
  }
}

extern "C" void kernel_launch(void* const* d_in, const int* in_sizes, int n_in,
                              void* d_out, int out_size, void* d_ws, size_t ws_size,
                              hipStream_t stream) {
  const float* x = (const float*)d_in[0];
  const float* cosb = (const float*)d_in[1];
  const float* sinb = (const float*)d_in[2];
  const float* qw = (const float*)d_in[3];
  const float* kw = (const float*)d_in[4];
  const float* vw = (const float*)d_in[5];
  const float* ow = (const float*)d_in[6];
  const float* rawW = (const float*)d_in[7];
  const float* wsc = (const float*)d_in[8];
  const float* gm = (const float*)d_in[9];
  float* out = (float*)d_out;

  char* ws = (char*)d_ws;
  u16* xb = (u16*)(ws);                      // 16 MB f16 x (reused as normed)
  u16* wcat = (u16*)(ws + (16ull << 20));    // 12 MB f16 [qw;kw;vw]
  u16* wo16 = (u16*)(ws + (28ull << 20));    // 8 MB f16 out_w
  float* invw = (float*)(ws + (36ull << 20));// 1 MB
  u16* qp = (u16*)(ws + (84ull << 20));      // 16 MB
  u16* kp = (u16*)(ws + (100ull << 20));     // 4 MB
  u16* vtp = (u16*)(ws + (104ull << 20));    // 4 MB
  u16* normed = xb;

  cvt_all<<<dim3(8192, 5), 256, 0, stream>>>(x, qw, kw, vw, ow, xb, wcat, wo16);
  gemm_qkv_rope<<<dim3(24, 32), 256, 0, stream>>>(xb, wcat, cosb, sinb, qp, kp, vtp);
  lstats_kernel<<<dim3(16, H_, B_ * M_), 256, 0, stream>>>(qp, kp, rawW, wsc, invw);
  attn_kernel<<<dim3(64, H_, B_), 128, 0, stream>>>(qp, kp, vtp, invw, gm, normed);
  gemm_bt<<<dim3(2048 / 128, 4096 / 128), 256, 0, stream>>>(normed, wo16, out, 4096, 2048, 2048);
}

// Round 10
// 441.972 us; speedup vs baseline: 1.2211x; 1.2211x over previous
//
#include <hip/hip_runtime.h>

// MultiheadFlashLinearEnsemble: B=2,T=2048,E=2048,H=16,HKV=4,M=4,HD=32,NREP=4
// cvt_all->f16 -> GEMM+rope fused -> lstats (softmax denoms) ->
// attn v9: R8-proven v7 structure (128 thr, 32-row paired q-tiles, shared
// Pc, e-sliced PV, 2 barriers/iter) + raw v_exp_f32 via builtin + causal
// mask only on the diagonal k-tile. -> RMSnorm -> GEMM(out).

typedef unsigned short u16;
typedef unsigned int u32;
typedef _Float16 f16;
typedef _Float16 f16x8 __attribute__((ext_vector_type(8)));
typedef float f32x4 __attribute__((ext_vector_type(4)));

#define B_ 2
#define T_ 2048
#define E_ 2048
#define H_ 16
#define HKV_ 4
#define M_ 4
#define HD_ 32
// (1/sqrt(32)) * log2(e): q-scores in log2 domain -> v_exp_f32 directly
#define SCALE_Q 0.2550348873f

#define EXP2(x) __builtin_amdgcn_exp2f(x)

#define GLOAD_LDS(g, l)                                                   \
  __builtin_amdgcn_global_load_lds(                                       \
      (const __attribute__((address_space(1))) u32*)(g),                  \
      (__attribute__((address_space(3))) u32*)(l), 16, 0, 0)

__device__ __forceinline__ u16 f2h(float f) {
  f16 h = (f16)f;
  return __builtin_bit_cast(u16, h);
}

// One launch converts all five f32 tensors to f16 (blockIdx.y = region).
__global__ void cvt_all(const float* __restrict__ x, const float* __restrict__ qw,
                        const float* __restrict__ kw, const float* __restrict__ vw,
                        const float* __restrict__ ow, u16* __restrict__ xb,
                        u16* __restrict__ wcat, u16* __restrict__ wo16) {
  const float* src;
  u16* dst;
  int n4;
  switch (blockIdx.y) {
    case 0: src = x;  dst = xb;            n4 = 2097152; break;
    case 1: src = qw; dst = wcat;          n4 = 1048576; break;
    case 2: src = kw; dst = wcat + 4194304; n4 = 262144; break;
    case 3: src = vw; dst = wcat + 5242880; n4 = 262144; break;
    default: src = ow; dst = wo16;         n4 = 1048576; break;
  }
  int i = blockIdx.x * blockDim.x + threadIdx.x;
  if (i < n4) {
    float4 v = ((const float4*)src)[i];
    ushort4 o;
    o.x = f2h(v.x); o.y = f2h(v.y); o.z = f2h(v.z); o.w = f2h(v.w);
    ((ushort4*)dst)[i] = o;
  }
}

// ---- GEMM core macro: 128x128 tile, BK=32, acc[4][4] per wave ----
#define GEMM_CORE(A_, B_ptr, K_)                                              \
  for (int k0 = 0; k0 < (K_); k0 += 32) {                                     \
    _Pragma("unroll") for (int j = 0; j < 2; ++j) {                           \
      GLOAD_LDS(&(A_)[(size_t)(m0 + r0 + j * 64) * (K_) + k0 + c8],           \
                &As[tid * 8 + j * 2048]);                                     \
      GLOAD_LDS(&(B_ptr)[(size_t)(n0 + r0 + j * 64) * (K_) + k0 + c8],        \
                &Bs[tid * 8 + j * 2048]);                                     \
    }                                                                         \
    __syncthreads();                                                          \
    f16x8 af[4], bfr[4];                                                      \
    _Pragma("unroll") for (int mt = 0; mt < 4; ++mt)                          \
        af[mt] = *(const f16x8*)&As[(wm + mt * 16 + r) * 32 + g * 8];         \
    _Pragma("unroll") for (int nt = 0; nt < 4; ++nt)                          \
        bfr[nt] = *(const f16x8*)&Bs[(wn + nt * 16 + r) * 32 + g * 8];        \
    _Pragma("unroll") for (int mt = 0; mt < 4; ++mt)                          \
        _Pragma("unroll") for (int nt = 0; nt < 4; ++nt)                      \
            acc[mt][nt] = __builtin_amdgcn_mfma_f32_16x16x32_f16(             \
                af[mt], bfr[nt], acc[mt][nt], 0, 0, 0);                       \
    __syncthreads();                                                          \
  }

// out = normed @ out_w^T, plain f32 C write.
__global__ __launch_bounds__(256) void gemm_bt(const u16* __restrict__ A,
                                               const u16* __restrict__ Bm,
                                               float* __restrict__ C,
                                               int M, int N, int K) {
  __shared__ __align__(16) u16 As[128 * 32];
  __shared__ __align__(16) u16 Bs[128 * 32];
  const int tid = threadIdx.x;
  const int lane = tid & 63;
  const int wv = tid >> 6;
  const int g = lane >> 4;
  const int r = lane & 15;
  const int m0 = blockIdx.y * 128;
  const int n0 = blockIdx.x * 128;
  const int wm = (wv >> 1) * 64;
  const int wn = (wv & 1) * 64;
  f32x4 acc[4][4];
#pragma unroll
  for (int a = 0; a < 4; ++a)
#pragma unroll
    for (int b = 0; b < 4; ++b) acc[a][b] = (f32x4){0.f, 0.f, 0.f, 0.f};
  const int r0 = tid >> 2;
  const int c8 = (tid & 3) << 3;

  GEMM_CORE(A, Bm, K)

#pragma unroll
  for (int mt = 0; mt < 4; ++mt)
#pragma unroll
    for (int nt = 0; nt < 4; ++nt) {
      int row = m0 + wm + mt * 16 + g * 4;
      int col = n0 + wn + nt * 16 + r;
#pragma unroll
      for (int rr = 0; rr < 4; ++rr)
        C[(size_t)(row + rr) * N + col] = acc[mt][nt][rr];
    }
}

// qkv GEMM with FUSED rotary + repack epilogue. N=3072; each 128-col block
// lies wholly in one region: bx 0-15 q, 16-19 k, 20-23 v.
__global__ __launch_bounds__(256) void gemm_qkv_rope(
    const u16* __restrict__ A, const u16* __restrict__ Bm,
    const float* __restrict__ cosb, const float* __restrict__ sinb,
    u16* __restrict__ qp, u16* __restrict__ kp, u16* __restrict__ vtp) {
  __shared__ __align__(16) u16 As[128 * 32];
  __shared__ __align__(16) u16 Bs[128 * 32];
  const int tid = threadIdx.x;
  const int lane = tid & 63;
  const int wv = tid >> 6;
  const int g = lane >> 4;
  const int r = lane & 15;
  const int m0 = blockIdx.y * 128;
  const int n0 = blockIdx.x * 128;
  const int wm = (wv >> 1) * 64;
  const int wn = (wv & 1) * 64;
  f32x4 acc[4][4];
#pragma unroll
  for (int a = 0; a < 4; ++a)
#pragma unroll
    for (int b = 0; b < 4; ++b) acc[a][b] = (f32x4){0.f, 0.f, 0.f, 0.f};
  const int r0 = tid >> 2;
  const int c8 = (tid & 3) << 3;

  GEMM_CORE(A, Bm, 2048)

  const int b = m0 >> 11;                 // block-uniform batch
  const float signf = (r & 1) ? 1.f : -1.f;
  const int jb = r >> 1;                  // j for even nt; odd nt -> jb+8

  if (n0 < 2048) {
#pragma unroll
    for (int mt = 0; mt < 4; ++mt) {
      int row = m0 + wm + mt * 16 + g * 4;
      int t0 = row & 2047;
#pragma unroll
      for (int rr = 0; rr < 4; ++rr) {
        int t = t0 + rr;
        float c0 = cosb[t * 16 + jb], s0 = sinb[t * 16 + jb];
        float c1 = cosb[t * 16 + 8 + jb], s1 = sinb[t * 16 + 8 + jb];
#pragma unroll
        for (int nt = 0; nt < 4; ++nt) {
          float xv = acc[mt][nt][rr];
          float pv = __shfl_xor(xv, 1, 64);
          float c = (nt & 1) ? c1 : c0;
          float s = (nt & 1) ? s1 : s0;
          float o = (xv * c + signf * pv * s) * SCALE_Q;
          int col = n0 + wn + nt * 16 + r;
          int hh = col >> 7, mm = (col >> 5) & 3, d = col & 31;
          qp[((((size_t)b * H_ + hh) * M_ + mm) * T_ + t) * HD_ + d] = f2h(o);
        }
      }
    }
  } else if (n0 < 2560) {
#pragma unroll
    for (int mt = 0; mt < 4; ++mt) {
      int row = m0 + wm + mt * 16 + g * 4;
      int t0 = row & 2047;
#pragma unroll
      for (int rr = 0; rr < 4; ++rr) {
        int t = t0 + rr;
        float c0 = cosb[t * 16 + jb], s0 = sinb[t * 16 + jb];
        float c1 = cosb[t * 16 + 8 + jb], s1 = sinb[t * 16 + 8 + jb];
#pragma unroll
        for (int nt = 0; nt < 4; ++nt) {
          float xv = acc[mt][nt][rr];
          float pv = __shfl_xor(xv, 1, 64);
          float c = (nt & 1) ? c1 : c0;
          float s = (nt & 1) ? s1 : s0;
          float o = xv * c + signf * pv * s;
          int col2 = n0 + wn + nt * 16 + r - 2048;
          int hh = col2 >> 7, mm = (col2 >> 5) & 3, d = col2 & 31;
          kp[((((size_t)b * HKV_ + hh) * M_ + mm) * T_ + t) * HD_ + d] = f2h(o);
        }
      }
    }
  } else {
#pragma unroll
    for (int mt = 0; mt < 4; ++mt) {
      int row = m0 + wm + mt * 16 + g * 4;
      int t0 = row & 2047;
#pragma unroll
      for (int nt = 0; nt < 4; ++nt) {
        int col3 = n0 + wn + nt * 16 + r - 2560;
        int hkv = col3 >> 7, e = col3 & 127;
        ushort4 w;
        w.x = f2h(acc[mt][nt][0]);
        w.y = f2h(acc[mt][nt][1]);
        w.z = f2h(acc[mt][nt][2]);
        w.w = f2h(acc[mt][nt][3]);
        *(ushort4*)&vtp[(((size_t)b * HKV_ + hkv) * 128 + e) * T_ + t0] = w;
      }
    }
  }
}

// Softmax denom prepass: invw[b][h][e][row] = tanh(rawW[e])*ws / sum exp2(s').
// Wave = 16-row strip; PAIRED strips (s, 127-s). Mask only on diagonal tile.
__global__ __launch_bounds__(256) void lstats_kernel(
    const u16* __restrict__ qp, const u16* __restrict__ kp,
    const float* __restrict__ rawW, const float* __restrict__ wscale,
    float* __restrict__ invw) {
  const int tid = threadIdx.x;
  const int lane = tid & 63;
  const int wv = tid >> 6;
  const int g = lane >> 4, r = lane & 15;
  const int h = blockIdx.y;
  const int b = blockIdx.z >> 2, e = blockIdx.z & 3;
  const int hkv = h >> 2;
  const int s0 = blockIdx.x * 4 + wv;  // strip 0..63; pair = 127-s0

  const size_t qb = (((size_t)b * H_ + h) * M_ + e) * T_ * HD_;
  const size_t kb = (((size_t)b * HKV_ + hkv) * M_ + e) * T_ * HD_;
  const float mw = tanhf(rawW[e]) * wscale[0];

  for (int ps = 0; ps < 2; ++ps) {
    const int strip = ps ? 127 - s0 : s0;
    const int q0 = strip * 16;
    f16x8 qf = *(const f16x8*)&qp[qb + (size_t)(q0 + r) * HD_ + g * 8];
    float lacc[4] = {0.f, 0.f, 0.f, 0.f};

    // bulk tiles: no mask
    for (int k0 = 0; k0 + 63 <= q0; k0 += 64) {
      f32x4 s[4];
#pragma unroll
      for (int nt = 0; nt < 4; ++nt) {
        f16x8 kf = *(const f16x8*)&kp[kb + (size_t)(k0 + nt * 16 + r) * HD_ + g * 8];
        s[nt] = __builtin_amdgcn_mfma_f32_16x16x32_f16(qf, kf, (f32x4){0.f, 0.f, 0.f, 0.f}, 0, 0, 0);
      }
#pragma unroll
      for (int rr = 0; rr < 4; ++rr)
#pragma unroll
        for (int nt = 0; nt < 4; ++nt) lacc[rr] += EXP2(s[nt][rr]);
    }
    // diagonal tile: masked
    {
      const int k0 = q0 & ~63;
      f32x4 s[4];
#pragma unroll
      for (int nt = 0; nt < 4; ++nt) {
        f16x8 kf = *(const f16x8*)&kp[kb + (size_t)(k0 + nt * 16 + r) * HD_ + g * 8];
        s[nt] = __builtin_amdgcn_mfma_f32_16x16x32_f16(qf, kf, (f32x4){0.f, 0.f, 0.f, 0.f}, 0, 0, 0);
      }
#pragma unroll
      for (int rr = 0; rr < 4; ++rr) {
        int row = q0 + g * 4 + rr;
#pragma unroll
        for (int nt = 0; nt < 4; ++nt) {
          int col = k0 + nt * 16 + r;
          lacc[rr] += (col <= row) ? EXP2(s[nt][rr]) : 0.f;
        }
      }
    }
#pragma unroll
    for (int rr = 0; rr < 4; ++rr) {
      float l = lacc[rr];
#pragma unroll
      for (int off = 8; off >= 1; off >>= 1) l += __shfl_xor(l, off, 64);
      if (r == 0)
        invw[(((size_t)b * H_ + h) * M_ + e) * T_ + q0 + g * 4 + rr] = mw / l;
    }
  }
}

// attn v9 (= R8 v7 + raw exp + diag-only mask): 128 threads (2 waves),
// 32-row q-tiles, paired (bx,63-bx) -> 1024 uniform blocks. Wave w: QK rows
// [16w,16w+16) x 4 ensembles combined in registers -> shared Pc[32][72];
// PV all 32 rows x e-slice [64w,64w+64). Single Ks, 2 barriers/iter.
__global__ __launch_bounds__(128) void attn_kernel(
    const u16* __restrict__ qp, const u16* __restrict__ kp,
    const u16* __restrict__ vtp, const float* __restrict__ invw,
    const float* __restrict__ gamma, u16* __restrict__ normed) {
  __shared__ __align__(16) char smem[20992];
  u16* Ks = (u16*)smem;            // [e][g2][kk][8] = 16 KB
  u16* Pc = (u16*)(smem + 16384);  // [32][72] = 4608 B
  float* comb = (float*)smem;      // [32][132] f32 = 16896 B (aliased)

  const int tid = threadIdx.x;
  const int lane = tid & 63;
  const int wv = tid >> 6;  // 0..1
  const int g = lane >> 4;
  const int r = lane & 15;
  const int h = blockIdx.y;
  const int b = blockIdx.z;
  const int hkv = h >> 2;

  const size_t qb = ((size_t)b * H_ + h) * M_ * T_ * HD_;
  const size_t kb = ((size_t)b * HKV_ + hkv) * M_ * T_ * HD_;
  const size_t vb = ((size_t)b * HKV_ + hkv) * 128 * (size_t)T_;

#define STAGE_KS(K0)                                                          \
  {                                                                           \
    _Pragma("unroll") for (int j = 0; j < 8; ++j) {                           \
      int f = tid + j * 128;                                                  \
      int e_ = f >> 8, g2 = (f >> 6) & 3, kk = f & 63;                        \
      GLOAD_LDS(&kp[kb + ((size_t)e_ * T_ + (K0) + kk) * HD_ + g2 * 8],       \
                &Ks[f * 8]);                                                  \
    }                                                                         \
  }

  // one k-tile iteration body; MASKED = diagonal tile
#define ATTN_ITER(K0, I, NITER, MASKED)                                       \
  {                                                                           \
    f16x8 vf[2][4];                                                           \
    _Pragma("unroll") for (int ct = 0; ct < 4; ++ct)                          \
        _Pragma("unroll") for (int k2 = 0; k2 < 2; ++k2)                      \
            vf[k2][ct] = *(const f16x8*)&vtp[vb +                             \
                (size_t)(wv * 64 + ct * 16 + r) * T_ + (K0) + k2 * 32 + g * 8]; \
    float pc[4][4];                                                           \
    _Pragma("unroll") for (int nt = 0; nt < 4; ++nt)                          \
        _Pragma("unroll") for (int rr = 0; rr < 4; ++rr) pc[nt][rr] = 0.f;    \
    _Pragma("unroll") for (int e = 0; e < 4; ++e) {                           \
      f32x4 s[4];                                                             \
      _Pragma("unroll") for (int nt = 0; nt < 4; ++nt) {                      \
        f16x8 kf = *(const f16x8*)&Ks[e * 2048 + g * 512 + (nt * 16 + r) * 8];\
        s[nt] = __builtin_amdgcn_mfma_f32_16x16x32_f16(                       \
            qf[e], kf, (f32x4){0.f, 0.f, 0.f, 0.f}, 0, 0, 0);                 \
      }                                                                       \
      _Pragma("unroll") for (int nt = 0; nt < 4; ++nt)                        \
          _Pragma("unroll") for (int rr = 0; rr < 4; ++rr) {                  \
            float sv = s[nt][rr];                                             \
            if (MASKED && ((K0) + nt * 16 + r > rq + g * 4 + rr)) sv = -1e30f;\
            pc[nt][rr] = fmaf(EXP2(sv), iw[e][rr], pc[nt][rr]);               \
          }                                                                   \
    }                                                                         \
    __syncthreads(); /* A: Ks reads done */                                   \
    _Pragma("unroll") for (int nt = 0; nt < 4; ++nt)                          \
        _Pragma("unroll") for (int rr = 0; rr < 4; ++rr)                      \
            Pc[(wv * 16 + g * 4 + rr) * 72 + nt * 16 + r] = f2h(pc[nt][rr]);  \
    if ((I) + 1 < (NITER)) STAGE_KS((K0) + 64);                               \
    __syncthreads(); /* B: Pc visible; Ks(next) landed */                     \
    _Pragma("unroll") for (int mt = 0; mt < 2; ++mt) {                        \
      f16x8 pf0 = *(const f16x8*)&Pc[(mt * 16 + r) * 72 + g * 8];             \
      f16x8 pf1 = *(const f16x8*)&Pc[(mt * 16 + r) * 72 + 32 + g * 8];        \
      _Pragma("unroll") for (int ct = 0; ct < 4; ++ct) {                      \
        acc[mt][ct] = __builtin_amdgcn_mfma_f32_16x16x32_f16(                 \
            pf0, vf[0][ct], acc[mt][ct], 0, 0, 0);                            \
        acc[mt][ct] = __builtin_amdgcn_mfma_f32_16x16x32_f16(                 \
            pf1, vf[1][ct], acc[mt][ct], 0, 0, 0);                            \
      }                                                                       \
    }                                                                         \
  }

  for (int ps = 0; ps < 2; ++ps) {
    const int q0 = (ps ? 63 - blockIdx.x : blockIdx.x) * 32;
    const int rq = q0 + wv * 16;  // wave's first q-row

    f16x8 qf[4];
    float iw[4][4];
#pragma unroll
    for (int e = 0; e < 4; ++e) {
      qf[e] = *(const f16x8*)&qp[qb + ((size_t)e * T_ + rq + r) * HD_ + g * 8];
      const float* ivp = invw + (((size_t)b * H_ + h) * M_ + e) * T_;
#pragma unroll
      for (int rr = 0; rr < 4; ++rr) iw[e][rr] = ivp[rq + g * 4 + rr];
    }

    // acc[mt][ct]: row = mt*16+g*4+rr (block rows), col = wv*64+ct*16+r
    f32x4 acc[2][4];
#pragma unroll
    for (int mt = 0; mt < 2; ++mt)
#pragma unroll
      for (int ct = 0; ct < 4; ++ct) acc[mt][ct] = (f32x4){0.f, 0.f, 0.f, 0.f};

    __syncthreads();  // prev pass's comb reads done before Ks overwrite
    STAGE_KS(0);
    __syncthreads();  // K(0) landed

    const int niter = q0 / 64 + 1;
    // bulk tiles: every k-col <= every row (k0+63 <= q0 <= rq) -> no mask
    for (int i = 0; i < niter - 1; ++i) ATTN_ITER(i * 64, i, niter, false);
    // diagonal tile
    ATTN_ITER((niter - 1) * 64, niter - 1, niter, true);

    __syncthreads();  // last PV reads of Pc done; alias smem as comb[32][132]
#pragma unroll
    for (int mt = 0; mt < 2; ++mt)
#pragma unroll
      for (int ct = 0; ct < 4; ++ct)
#pragma unroll
        for (int rr = 0; rr < 4; ++rr)
          comb[(mt * 16 + g * 4 + rr) * 132 + wv * 64 + ct * 16 + r] = acc[mt][ct][rr];
    __syncthreads();

    // RMSnorm: thread = (row = tid>>2 in 0..31, 32-col chunk ch = (tid&3)*32)
    {
      int row = tid >> 2;
      int ch = (tid & 3) * 32;
      float vals[32];
      float ss = 0.f;
#pragma unroll
      for (int e2 = 0; e2 < 32; ++e2) {
        float v = comb[row * 132 + ch + e2];
        vals[e2] = v;
        ss += v * v;
      }
      ss += __shfl_xor(ss, 1, 64);
      ss += __shfl_xor(ss, 2, 64);
      float rstd = rsqrtf(ss * (1.f / 128.f) + 1e-5f);
      size_t obase = ((size_t)b * T_ + q0 + row) * E_ + (size_t)h * 128 + ch;
      union { u16 u[32]; uint4 q[4]; } pk;
#pragma unroll
      for (int e2 = 0; e2 < 32; ++e2)
        pk.u[e2] = f2h(vals[e2] * rstd * gamma[ch + e2]);
#pragma unroll
      for (int qq = 0; qq < 4; ++qq)
        *(uint4*)&normed[obase + qq * 8] = pk.q[qq];
    }
  }
#undef ATTN_ITER
#undef STAGE_KS
}

extern "C" void kernel_launch(void* const* d_in, const int* in_sizes, int n_in,
                              void* d_out, int out_size, void* d_ws, size_t ws_size,
                              hipStream_t stream) {
  const float* x = (const float*)d_in[0];
  const float* cosb = (const float*)d_in[1];
  const float* sinb = (const float*)d_in[2];
  const float* qw = (const float*)d_in[3];
  const float* kw = (const float*)d_in[4];
  const float* vw = (const float*)d_in[5];
  const float* ow = (const float*)d_in[6];
  const float* rawW = (const float*)d_in[7];
  const float* wsc = (const float*)d_in[8];
  const float* gm = (const float*)d_in[9];
  float* out = (float*)d_out;

  char* ws = (char*)d_ws;
  u16* xb = (u16*)(ws);                      // 16 MB f16 x (reused as normed)
  u16* wcat = (u16*)(ws + (16ull << 20));    // 12 MB f16 [qw;kw;vw]
  u16* wo16 = (u16*)(ws + (28ull << 20));    // 8 MB f16 out_w
  float* invw = (float*)(ws + (36ull << 20));// 1 MB
  u16* qp = (u16*)(ws + (84ull << 20));      // 16 MB
  u16* kp = (u16*)(ws + (100ull << 20));     // 4 MB
  u16* vtp = (u16*)(ws + (104ull << 20));    // 4 MB
  u16* normed = xb;

  cvt_all<<<dim3(8192, 5), 256, 0, stream>>>(x, qw, kw, vw, ow, xb, wcat, wo16);
  gemm_qkv_rope<<<dim3(24, 32), 256, 0, stream>>>(xb, wcat, cosb, sinb, qp, kp, vtp);
  lstats_kernel<<<dim3(16, H_, B_ * M_), 256, 0, stream>>>(qp, kp, rawW, wsc, invw);
  attn_kernel<<<dim3(32, H_, B_), 128, 0, stream>>>(qp, kp, vtp, invw, gm, normed);
  gemm_bt<<<dim3(2048 / 128, 4096 / 128), 256, 0, stream>>>(normed, wo16, out, 4096, 2048, 2048);
}